// Round 11
// baseline (28724.484 us; speedup 1.0000x reference)
//
#include <hip/hip_runtime.h>
#include <hip/hip_cooperative_groups.h>
#include <hip/hip_bf16.h>

namespace cg = cooperative_groups;

typedef __hip_bfloat16 bf16;
typedef __attribute__((ext_vector_type(8))) short s16x8;
typedef __attribute__((ext_vector_type(4))) float f32x4;

// Problem constants
#define TT 55
#define BB 512
#define DD 512
#define KK 64
#define NHS 8                    // h ring slots
#define LDH ((long)NHS*1536)     // h ring row stride
#define SZG ((long)BB*2048)
#define SZR ((long)BB*64)
#define GRID 1024                // 4 blocks/CU x 256 CUs, guaranteed co-resident

typedef const __attribute__((address_space(1))) unsigned int gu32;
typedef __attribute__((address_space(3))) unsigned int lu32;
__device__ __forceinline__ void gload16(const void* g, void* l) {
  __builtin_amdgcn_global_load_lds((gu32*)g, (lu32*)l, 16, 0, 0);
}

struct PArgs {
  const bf16 *xb, *WL0T, *WL1T, *WL2T, *projT, *hz;
  bf16 *HallR;
  float *accg, *accr, *ubuf, *cbuf, *dbuf;
  const float *biasg, *wd, *proj_b;
  float *dump, *out;
};

__device__ __forceinline__ float sigm(float x){ return 1.0f/(1.0f + __expf(-x)); }
__device__ __forceinline__ float ftanh(float x){ float e = __expf(2.0f*x); return 1.0f - 2.0f/(e + 1.0f); }

// ---------------- cell worker: (s,l), batch rows [rb*2, rb*2+2)
__device__ __forceinline__ void cell_work(const PArgs& P, int s, int l, int rb,
                                          float dn[2][64])
{
  const float* gate = P.accg + ((long)((s&3)*3+l))*SZG;
  const float* gr   = P.accr + ((long)((s&3)*3+l))*SZR;
  const float* u0 = (l>=1) ? P.ubuf + ((long)(((s-1)&3)*2+0))*SZR : nullptr;
  const float* u1 = (l>=2) ? P.ubuf + ((long)(((s-1)&3)*2+1))*SZR : nullptr;
  float* c = P.cbuf + (long)l*BB*DD;
  float* d = P.dbuf + (long)l*BB*KK;
  bf16* hout = P.HallR + (long)(s % NHS)*1536 + (long)l*512;
  const int tid = threadIdx.x;
  const long r0 = (long)rb*2;

  if (tid < 128) {
    int r = tid >> 6, k = tid & 63;
    long row = r0 + r;
    float gv = gr[row*64 + k];
    if (u0) gv += (1.0f/3.0f)*u0[row*64 + k];
    if (u1) gv += (1.0f/3.0f)*u1[row*64 + k];
    float rr = sigm(gv);
    float dv = rr * d[row*64 + k];
    d[row*64 + k] = dv;
    dn[r][k] = dv;
  }
  __syncthreads();

  float accv[2][2] = {};
#pragma unroll 4
  for (int k = 0; k < 64; ++k) {
    float w0 = P.wd[k*512 + tid];
    float w1 = P.wd[k*512 + tid + 256];
#pragma unroll
    for (int r = 0; r < 2; ++r) {
      float dv = dn[r][k];
      accv[0][r] += dv * w0;
      accv[1][r] += dv * w1;
    }
  }

#pragma unroll
  for (int half = 0; half < 2; ++half) {
    int n = tid + half*256;
#pragma unroll
    for (int r = 0; r < 2; ++r) {
      long row = r0 + r;
      const float* gg = gate + row*2048;
      float fv = sigm(gg[n]);
      float iv = sigm(gg[512+n]);
      float ov = sigm(gg[1024+n]);
      float cb = ftanh(gg[1536+n]);
      float cv = fv * c[row*512 + n] + iv * cb + ftanh(accv[half][r]);
      c[row*512 + n] = cv;
      hout[row*LDH + n] = __float2bfloat16(ov * ftanh(cv));
    }
  }
}

// ---------------- tile descriptor + worker (r10's proven 64x64 single-barrier loop)
struct TDesc {
  const bf16* Ap[4]; long lap[4];
  const bf16* Bm; long ldb; int K;
  float* dst; long ldd; int cb0;
  const float* bias;
  long m0, n0;
};

// build descriptor for group gidx at phase t, tile index `local` (mt-fast).
// returns false if group inactive this phase.
__device__ __forceinline__ bool build_tdesc(const PArgs& P, int gidx, int t,
                                            int local, TDesc& td)
{
  int mt = local & 7, nt = local >> 3;
  td.m0 = (long)mt*64; td.n0 = (long)nt*64;
  if (gidx == 0) {                       // L0 -> step t+1, A=[x(t+1); h0(t)]
    if (t < -1 || t > TT-2) return false;
    td.Ap[0] = P.xb + (long)(t+1)*BB*512; td.lap[0] = 512;
    td.Ap[1] = (t>=0) ? P.HallR + (long)(t % NHS)*1536 : P.hz;
    td.lap[1] = (t>=0) ? LDH : 512;
    td.Bm = P.WL0T; td.ldb = 1024; td.K = 1024;
    if (nt < 32)      { td.dst = P.accg + ((long)(((t+1)&3)*3+0))*SZG; td.ldd=2048; td.cb0=0;    td.bias = P.biasg; }
    else if (nt == 32){ td.dst = P.accr + ((long)(((t+1)&3)*3+0))*SZR; td.ldd=64;   td.cb0=2048; td.bias = nullptr; }
    else              { td.dst = P.ubuf + ((long)((t&3)*2+0))*SZR;     td.ldd=64;   td.cb0=2112; td.bias = nullptr; }
  } else if (gidx == 1) {                // L1 -> step t, A=[x(t); h0(t); h1(t-1)]
    if (t < 0 || t > TT-1) return false;
    td.Ap[0] = P.xb + (long)t*BB*512; td.lap[0] = 512;
    td.Ap[1] = P.HallR + (long)(t % NHS)*1536; td.lap[1] = LDH;
    td.Ap[2] = (t>=1) ? P.HallR + (long)((t-1) % NHS)*1536 + 512 : P.hz;
    td.lap[2] = (t>=1) ? LDH : 512;
    td.Bm = P.WL1T; td.ldb = 1536; td.K = 1536;
    if (nt < 32)      { td.dst = P.accg + ((long)((t&3)*3+1))*SZG;     td.ldd=2048; td.cb0=0;    td.bias = P.biasg + 2048; }
    else if (nt == 32){ td.dst = P.accr + ((long)((t&3)*3+1))*SZR;     td.ldd=64;   td.cb0=2048; td.bias = nullptr; }
    else              { td.dst = P.ubuf + ((long)(((t-1)&3)*2+1))*SZR; td.ldd=64;   td.cb0=2112; td.bias = nullptr; }
  } else if (gidx == 2) {                // L2 -> step s=t-1, A=[x(s); h0(s); h1(s); h2(s-1)]
    if (t < 1 || t > TT) return false;
    int s = t-1;
    td.Ap[0] = P.xb + (long)s*BB*512; td.lap[0] = 512;
    td.Ap[1] = P.HallR + (long)(s % NHS)*1536;       td.lap[1] = LDH;
    td.Ap[2] = P.HallR + (long)(s % NHS)*1536 + 512; td.lap[2] = LDH;
    td.Ap[3] = (s>=1) ? P.HallR + (long)((s-1) % NHS)*1536 + 1024 : P.hz;
    td.lap[3] = (s>=1) ? LDH : 512;
    td.Bm = P.WL2T; td.ldb = 2048; td.K = 2048;
    if (nt < 32)      { td.dst = P.accg + ((long)((s&3)*3+2))*SZG; td.ldd=2048; td.cb0=0;    td.bias = P.biasg + 4096; }
    else if (nt == 32){ td.dst = P.accr + ((long)((s&3)*3+2))*SZR; td.ldd=64;   td.cb0=2048; td.bias = nullptr; }
    else              { td.dst = P.dump;                           td.ldd=64;   td.cb0=2112; td.bias = nullptr; }
  } else {                               // proj -> step s=t-2, A=[h(t-2)]
    if (t < 2 || t > TT+1) return false;
    int s = t-2;
    td.Ap[0] = P.HallR + (long)(s % NHS)*1536;        td.lap[0] = LDH;
    td.Ap[1] = P.HallR + (long)(s % NHS)*1536 + 512;  td.lap[1] = LDH;
    td.Ap[2] = P.HallR + (long)(s % NHS)*1536 + 1024; td.lap[2] = LDH;
    td.Bm = P.projT; td.ldb = 1536; td.K = 1536;
    td.dst = P.out + (long)s*512; td.ldd = (long)TT*512; td.cb0 = 0; td.bias = P.proj_b;
  }
  return true;
}

__device__ __forceinline__ void tile_work(const TDesc& td,
                                          bf16 (*As)[64][64], bf16 (*Bs)[64][64])
{
  const int tid  = threadIdx.x;
  const int wave = tid >> 6, lane = tid & 63;
  const int q = lane >> 4, mm = lane & 15;
  const int s7 = mm & 7;
  const int wm = wave >> 1, wn = wave & 1;
  const int l8 = lane >> 3;
  const int gc = ((lane & 7) ^ l8) << 3;
  const bf16* Bb = td.Bm + td.n0 * td.ldb;
  const int nk = td.K >> 6;

  auto stage = [&](int bsel, int k0) {
    const int p = k0 >> 9;
    const long ldap = td.lap[p];
    const bf16* Abp = td.Ap[p] + td.m0 * ldap;
    const int ko = k0 & 511;
#pragma unroll
    for (int pp = 0; pp < 2; ++pp) {
      int r = pp*32 + wave*8;
      gload16(Abp + (long)(r + l8)*ldap + ko + gc, &As[bsel][r][0]);
    }
#pragma unroll
    for (int pp = 0; pp < 2; ++pp) {
      int r = pp*32 + wave*8;
      gload16(Bb + (long)(r + l8)*td.ldb + k0 + gc, &Bs[bsel][r][0]);
    }
  };

  f32x4 acc[2][2] = {};
  stage(0, 0);
  asm volatile("s_waitcnt vmcnt(0)" ::: "memory");
  __builtin_amdgcn_s_barrier();
  for (int k = 0; k < nk; ++k) {
    const int cur = k & 1;
    if (k + 1 < nk) stage(cur ^ 1, (k + 1) << 6);
#pragma unroll
    for (int kk = 0; kk < 64; kk += 32) {
      const int pc = ((((kk >> 3) + q) ^ s7) << 3);
      s16x8 av[2], bv[2];
#pragma unroll
      for (int i = 0; i < 2; ++i) av[i] = *(const s16x8*)&As[cur][wm*32 + i*16 + mm][pc];
#pragma unroll
      for (int j = 0; j < 2; ++j) bv[j] = *(const s16x8*)&Bs[cur][wn*32 + j*16 + mm][pc];
#pragma unroll
      for (int i = 0; i < 2; ++i)
#pragma unroll
        for (int j = 0; j < 2; ++j)
          acc[i][j] = __builtin_amdgcn_mfma_f32_16x16x32_bf16(av[i], bv[j], acc[i][j], 0,0,0);
    }
    if (k + 1 < nk) {
      asm volatile("s_waitcnt vmcnt(0)" ::: "memory");
      __builtin_amdgcn_s_barrier();
    }
  }

  int dcol0 = (int)td.n0 - td.cb0;
#pragma unroll
  for (int j = 0; j < 2; ++j) {
    int dcol = dcol0 + wn*32 + j*16 + mm;
    float bv = td.bias ? td.bias[dcol] : 0.0f;
#pragma unroll
    for (int i = 0; i < 2; ++i) {
      f32x4 a = acc[i][j];
#pragma unroll
      for (int r = 0; r < 4; ++r) {
        long row = td.m0 + wm*32 + i*16 + q*4 + r;
        td.dst[row * td.ldd + dcol] = a[r] + bv;
      }
    }
  }
}

// ---------------- persistent cooperative recurrence.
// Grid 1024 (4/CU guaranteed: 33 KB LDS, launch_bounds VGPR cap). Per phase t:
//   A: blocks [l*256, l*256+256) run cell E_l(t-l); others idle.
//   B: blocks [0,272) L0 | [272,544) L1 | [544,816) L2 | [816,880) proj.
// Fixed block->tile assignment across phases -> each XCD's L2 keeps its weight
// panels resident (~2.7 MB/XCD), killing the per-phase weight re-stream.
// __threadfence (release) + grid.sync (device-scope acquire) orders cross-XCD.
__global__ __launch_bounds__(256, 4) void persist(PArgs P)
{
  cg::grid_group gg = cg::this_grid();
  __shared__ __align__(16) bf16 As[2][64][64];    // 16 KB
  __shared__ __align__(16) bf16 Bs[2][64][64];    // 16 KB
  __shared__ float dn[2][64];                     // 512 B
  const int b = (int)blockIdx.x;

  for (int t = -1; t <= TT + 1; ++t) {
    // ----- A phase: cells
    if (b < 768) {
      int l = b >> 8, s = t - l;
      if (s >= 0 && s < TT) cell_work(P, s, l, b & 255, dn);
    }
    __threadfence();
    gg.sync();

    // ----- B phase: GEMM tiles
    {
      int gidx = -1, local = 0;
      if (b < 272)      { gidx = 0; local = b; }
      else if (b < 544) { gidx = 1; local = b - 272; }
      else if (b < 816) { gidx = 2; local = b - 544; }
      else if (b < 880) { gidx = 3; local = b - 816; }
      TDesc td;
      if (gidx >= 0 && build_tdesc(P, gidx, t, local, td))
        tile_work(td, As, Bs);
    }
    __threadfence();
    gg.sync();
  }
}

// ---------------- fallback per-phase wrappers (used only if cooperative launch
// is rejected by the runtime/graph capture - keeps the proven r10 behavior)
__global__ __launch_bounds__(256) void phaseA(PArgs P, int t)
{
  __shared__ float dn[2][64];
  int b = (int)blockIdx.x;
  int l = b >> 8, s = t - l;
  if (l < 3 && s >= 0 && s < TT) cell_work(P, s, l, b & 255, dn);
}
__global__ __launch_bounds__(256) void phaseB(PArgs P, int t)
{
  __shared__ __align__(16) bf16 As[2][64][64];
  __shared__ __align__(16) bf16 Bs[2][64][64];
  int b = (int)blockIdx.x;
  int gidx = -1, local = 0;
  if (b < 272)      { gidx = 0; local = b; }
  else if (b < 544) { gidx = 1; local = b - 272; }
  else if (b < 816) { gidx = 2; local = b - 544; }
  else if (b < 880) { gidx = 3; local = b - 816; }
  TDesc td;
  if (gidx >= 0 && build_tdesc(P, gidx, t, local, td))
    tile_work(td, As, Bs);
}

// ---------------- setup kernels
__global__ void k_tpose2(const float* __restrict__ src, long srow,
                         bf16* __restrict__ dst, long drow, int kcnt, long koff,
                         long total)
{
  long idx = (long)blockIdx.x * 256 + threadIdx.x;
  if (idx >= total) return;
  long n = idx / kcnt;
  long k = idx - n * kcnt;
  dst[n*drow + koff + k] = __float2bfloat16(src[k * srow + n]);
}

__global__ void k_xconv(const float* __restrict__ x, bf16* __restrict__ xb)
{
  long i = (long)blockIdx.x * 256 + threadIdx.x;
  if (i >= (long)TT*BB*512) return;
  int cc = (int)(i & 511);
  long r = i >> 9;
  int t = (int)(r / BB), b = (int)(r - (long)t*BB);
  xb[i] = __float2bfloat16(x[((long)b*TT + t)*512 + cc]);
}

__global__ void k_bias(const float* b0,const float* b1,const float* b2,
                       const float* b3,const float* b4,const float* b5,
                       float* out)
{
  int i = blockIdx.x*256 + threadIdx.x;
  if (i < 2048)      out[i] = b0[i] + b1[i];
  else if (i < 4096) out[i] = b2[i-2048] + b3[i-2048];
  else if (i < 6144) out[i] = b4[i-4096] + b5[i-4096];
}

__global__ void k_dinit(const float* __restrict__ keys, float* __restrict__ d)
{
  int i = blockIdx.x*256 + threadIdx.x;
  if (i < 3*BB*KK) d[i] = keys[i % (BB*KK)];
}

// ---------------- host
extern "C" void kernel_launch(void* const* d_in, const int* in_sizes, int n_in,
                              void* d_out, int out_size, void* d_ws, size_t ws_size,
                              hipStream_t stream)
{
  const float* inputs    = (const float*)d_in[0];
  const float* init_keys = (const float*)d_in[1];
  const float* wx_w[3] = {(const float*)d_in[2],  (const float*)d_in[8],  (const float*)d_in[14]};
  const float* wx_b[3] = {(const float*)d_in[3],  (const float*)d_in[9],  (const float*)d_in[15]};
  const float* wh_w[3] = {(const float*)d_in[4],  (const float*)d_in[10], (const float*)d_in[16]};
  const float* wh_b[3] = {(const float*)d_in[5],  (const float*)d_in[11], (const float*)d_in[17]};
  const float* wr_w[3] = {(const float*)d_in[6],  (const float*)d_in[12], (const float*)d_in[18]};
  const float* wl_w[3] = {(const float*)d_in[7],  (const float*)d_in[13], (const float*)d_in[19]};
  const float* wd_w   = (const float*)d_in[20];
  const float* proj_w = (const float*)d_in[21];
  const float* proj_b = (const float*)d_in[22];
  float* out = (float*)d_out;

  char* wsp = (char*)d_ws;
  size_t used = 0;
  auto alloc = [&](size_t bytes) {
    char* p = wsp + used;
    used += (bytes + 255) & ~(size_t)255;
    return p;
  };
  bf16* xb    = (bf16*)alloc((size_t)TT*BB*512*2);       // [t][b][c]
  bf16* WL0T  = (bf16*)alloc((size_t)2176*1024*2);       // [gate0|gr0|u0] x [x;h0]
  bf16* WL1T  = (bf16*)alloc((size_t)2176*1536*2);       // [gate1|gr1|u1] x [x;h0;h1]
  bf16* WL2T  = (bf16*)alloc((size_t)2176*2048*2);       // [gate2|gr2|pad] x [x;h0;h1;h2]
  bf16* projT = (bf16*)alloc((size_t)512*1536*2);
  bf16* HallR = (bf16*)alloc((size_t)BB*NHS*1536*2);     // h ring [b][slot][3*512]
  bf16* hz    = (bf16*)alloc((size_t)BB*512*2);          // zero h
  float* accg = (float*)alloc((size_t)4*3*BB*2048*4);    // gate rings
  float* accr = (float*)alloc((size_t)4*3*BB*64*4);      // gr rings
  float* ubuf = (float*)alloc((size_t)4*2*BB*64*4);      // u rings
  float* cbuf = (float*)alloc((size_t)3*BB*DD*4);
  float* dbuf = (float*)alloc((size_t)3*BB*KK*4);
  float* biasg= (float*)alloc((size_t)3*2048*4);
  float* dump = (float*)alloc((size_t)BB*64*4);
  if (used > ws_size) return;

  // ---- setup
  {
    long tot = (long)TT*BB*512;
    k_xconv<<<dim3((tot + 255)/256), 256, 0, stream>>>(inputs, xb);
  }
  hipMemsetAsync(WL0T, 0, (size_t)2176*1024*2, stream);
  hipMemsetAsync(WL1T, 0, (size_t)2176*1536*2, stream);
  hipMemsetAsync(WL2T, 0, (size_t)2176*2048*2, stream);
  hipMemsetAsync(hz,   0, (size_t)BB*512*2, stream);
  hipMemsetAsync(cbuf, 0, (size_t)3*BB*DD*4, stream);

  auto tp2 = [&](const float* src, long kOffSrc, long srow,
                 bf16* dst, long colbase, long drow, long koff, int N){
    long total = (long)N*512;
    k_tpose2<<<dim3((total + 255)/256), 256, 0, stream>>>(
        src + kOffSrc*srow, srow, dst + colbase*drow, drow, 512, koff, total);
  };
  // WL0T (drow=1024, K=[x;h0]): cols [gate0 2048 | gr0 64 | u0 64]
  tp2(wx_w[0],0,2048, WL0T,0,1024,0,2048);
  tp2(wh_w[0],0,2048, WL0T,0,1024,512,2048);
  tp2(wr_w[0],0,64,   WL0T,2048,1024,0,64);
  tp2(wl_w[0],0,64,   WL0T,2112,1024,512,64);
  // WL1T (drow=1536, K=[x;h0;h1]): cols [gate1 | gr1 | u1]
  tp2(wx_w[1],0,2048,   WL1T,0,1536,0,2048);
  tp2(wx_w[1],512,2048, WL1T,0,1536,512,2048);
  tp2(wh_w[1],0,2048,   WL1T,0,1536,1024,2048);
  tp2(wr_w[1],0,64,     WL1T,2048,1536,0,64);
  tp2(wr_w[1],512,64,   WL1T,2048,1536,512,64);
  tp2(wl_w[1],0,64,     WL1T,2112,1536,1024,64);
  // WL2T (drow=2048, K=[x;h0;h1;h2]): cols [gate2 | gr2 | pad]
  tp2(wx_w[2],0,2048,    WL2T,0,2048,0,2048);
  tp2(wx_w[2],512,2048,  WL2T,0,2048,512,2048);
  tp2(wx_w[2],1024,2048, WL2T,0,2048,1024,2048);
  tp2(wh_w[2],0,2048,    WL2T,0,2048,1536,2048);
  tp2(wr_w[2],0,64,      WL2T,2048,2048,0,64);
  tp2(wr_w[2],512,64,    WL2T,2048,2048,512,64);
  tp2(wr_w[2],1024,64,   WL2T,2048,2048,1024,64);
  // projT (drow=1536, K=[h0;h1;h2])
  {
    long total = (long)512*1536;
    k_tpose2<<<dim3((total + 255)/256), 256, 0, stream>>>(
        proj_w, 512, projT, 1536, 1536, 0, total);
  }

  k_bias<<<dim3(24),256,0,stream>>>(wx_b[0],wh_b[0],wx_b[1],wh_b[1],wx_b[2],wh_b[2], biasg);
  k_dinit<<<dim3((3*BB*KK + 255)/256),256,0,stream>>>(init_keys, dbuf);

  PArgs pa;
  pa.xb = xb; pa.WL0T = WL0T; pa.WL1T = WL1T; pa.WL2T = WL2T; pa.projT = projT;
  pa.hz = hz; pa.HallR = HallR;
  pa.accg = accg; pa.accr = accr; pa.ubuf = ubuf; pa.cbuf = cbuf; pa.dbuf = dbuf;
  pa.biasg = biasg; pa.wd = wd_w; pa.proj_b = proj_b; pa.dump = dump; pa.out = out;

  void* kargs[] = { (void*)&pa };
  hipError_t err = hipLaunchCooperativeKernel((const void*)persist,
                                              dim3(GRID), dim3(256),
                                              kargs, 0, stream);
  if (err != hipSuccess) {
    // fallback: proven r10-style per-phase launch loop (same workers)
    for (int t = -1; t <= TT + 1; ++t) {
      if (t >= 0 && t <= TT + 1)
        phaseA<<<dim3(768), 256, 0, stream>>>(pa, t);
      phaseB<<<dim3(880), 256, 0, stream>>>(pa, t);
    }
  }
}

// Round 12
// 2549.090 us; speedup vs baseline: 11.2685x; 11.2685x over previous
//
#include <hip/hip_runtime.h>
#include <hip/hip_bf16.h>

typedef __hip_bfloat16 bf16;
typedef __attribute__((ext_vector_type(8))) short s16x8;
typedef __attribute__((ext_vector_type(4))) float f32x4;

// Problem constants
#define TT 55
#define BB 512
#define DD 512
#define KK 64
#define LDH ((long)TT*1536)      // h buffer row stride (all 55 steps kept)

typedef const __attribute__((address_space(1))) unsigned int gu32;
typedef __attribute__((address_space(3))) unsigned int lu32;
__device__ __forceinline__ void gload16(const void* g, void* l) {
  __builtin_amdgcn_global_load_lds((gu32*)g, (lu32*)l, 16, 0, 0);
}

struct Seg {
  void*  dst;          // destination base
  long   ldd;          // row stride (elements)
  int    col_begin;    // inclusive (GEMM N space), 64-aligned, sorted asc
  int    mode;         // 0 = f32 store (+bias)
  const float* bias;   // indexed by (col - col_begin), may be null
};
struct SegList { Seg s[4]; int n; };

// A operand is split into up to 4 K-parts of exactly 512 columns each
// (x slice / h slices / zero buffer). B is one stacked-transposed buffer.
struct GDesc {
  const bf16* Ap[4]; const bf16* B;
  long ldap[4], ldb;
  int mtiles, ntiles, tile_beg, K;
  SegList segs;
};
struct GArgs { GDesc g[4]; int ng; int total; int chunk; };

// ---------------- batched GEMM: C[seg] = sum_p Ap[MxK_p] * B^T[NxK], bf16, fp32 acc
// 64x64 tile (r7 session optimum: 32x64 regressed on per-step fixed costs, 64x128
// on TLP), BK=64, 4 waves (2x2 of 32x32), 32 KB LDS, depth-1 double buffer with
// counted vmcnt(4). Equal-block-count XCD chunks (work-balanced variant regressed).
// LDS XOR-swizzled (block p of row r holds global block p^(r&7)).
__global__ __launch_bounds__(256) void gemm_batched(GArgs args)
{
  __shared__ __align__(16) bf16 As[2][64][64];    // 2 x 8 KB
  __shared__ __align__(16) bf16 Bs[2][64][64];    // 2 x 8 KB

  int tile = (int)(blockIdx.x & 7) * args.chunk + (int)(blockIdx.x >> 3);
  if (tile >= args.total) return;

  int gi = 0;
  for (int i = 1; i < args.ng; ++i) if (tile >= args.g[i].tile_beg) gi = i;
  const GDesc& g = args.g[gi];
  const int local = tile - g.tile_beg;
  const int mt = local % g.mtiles;           // mt-fast: B panel shared by consecutive tiles
  const int nt = local / g.mtiles;

  const int tid  = threadIdx.x;
  const int wave = tid >> 6, lane = tid & 63;
  const int q = lane >> 4, mm = lane & 15;
  const int s7 = mm & 7;
  const int wm = wave >> 1, wn = wave & 1;
  const long m0 = (long)mt * 64;
  const long n0 = (long)nt * 64;

  const bf16* Bb = g.B + n0 * g.ldb;
  const long ldb = g.ldb;
  const int l8 = lane >> 3;                 // row within 8-row staging group
  const int gc = ((lane & 7) ^ l8) << 3;    // swizzled global col (elements)

  const int nk = g.K >> 6;                  // K-steps

  auto stage = [&](int b, int k0) {
    const int p = k0 >> 9;                  // 512-wide K-parts; 64-steps never cross
    const long ldap = g.ldap[p];
    const bf16* Abp = g.Ap[p] + m0 * ldap;
    const int ko = k0 & 511;
#pragma unroll
    for (int pp = 0; pp < 2; ++pp) {
      int r = pp*32 + wave*8;
      gload16(Abp + (long)(r + l8)*ldap + ko + gc, &As[b][r][0]);
    }
#pragma unroll
    for (int pp = 0; pp < 2; ++pp) {
      int r = pp*32 + wave*8;
      gload16(Bb + (long)(r + l8)*ldb + k0 + gc, &Bs[b][r][0]);
    }
  };

  f32x4 acc[2][2] = {};

  stage(0, 0);                              // 4 loads in flight
  for (int k = 0; k < nk; ++k) {
    const int cur = k & 1;
    if (k + 1 < nk) {
      stage(cur ^ 1, (k + 1) << 6);         // 8 in flight
      asm volatile("s_waitcnt vmcnt(4)" ::: "memory");   // k's 4 landed
    } else {
      asm volatile("s_waitcnt vmcnt(0)" ::: "memory");
    }
    __builtin_amdgcn_s_barrier();           // all waves' k-data in LDS
#pragma unroll
    for (int kk = 0; kk < 64; kk += 32) {
      const int pc = ((((kk >> 3) + q) ^ s7) << 3);  // physical col of logical kk+q*8
      s16x8 av[2], bv[2];
#pragma unroll
      for (int i = 0; i < 2; ++i) av[i] = *(const s16x8*)&As[cur][wm*32 + i*16 + mm][pc];
#pragma unroll
      for (int j = 0; j < 2; ++j) bv[j] = *(const s16x8*)&Bs[cur][wn*32 + j*16 + mm][pc];
#pragma unroll
      for (int i = 0; i < 2; ++i)
#pragma unroll
        for (int j = 0; j < 2; ++j)
          acc[i][j] = __builtin_amdgcn_mfma_f32_16x16x32_bf16(av[i], bv[j], acc[i][j], 0,0,0);
    }
    __builtin_amdgcn_s_barrier();           // buf cur free for restage at k+2
  }

  // epilogue: 64-wide tile lies in ONE segment (boundaries 64-aligned)
  Seg sg = g.segs.s[0];
  for (int i = 1; i < g.segs.n; ++i)
    if ((int)n0 >= g.segs.s[i].col_begin) sg = g.segs.s[i];
#pragma unroll
  for (int j = 0; j < 2; ++j) {
    int dcol = (int)n0 + wn*32 + j*16 + mm - sg.col_begin;
    float bv = sg.bias ? sg.bias[dcol] : 0.0f;
#pragma unroll
    for (int i = 0; i < 2; ++i) {
      f32x4 a = acc[i][j];
#pragma unroll
      for (int r = 0; r < 4; ++r) {
        long row = m0 + wm*32 + i*16 + q*4 + r;  // C/D: col=lane&15, row=q*4+reg
        ((float*)sg.dst)[row * sg.ldd + dcol] = a[r] + bv;
      }
    }
  }
}

// ---------------- batched cell update: up to 3 independent (step,layer) cells
struct CellDesc {
  const float* gate;   // fp32 ring [512][2048] - complete (bias + all parts)
  const float* gr;     // fp32 [512][64] - complete x+h parts
  const float* u0;     // may be null (ALPHA-scaled in cell)
  const float* u1;     // may be null
  float* c;            // [512][512]
  float* d;            // [512][64]
  bf16*  hout;         // row stride LDH
};
struct CArgs { CellDesc e[3]; int n; };

__device__ inline float sigm(float x){ return 1.0f/(1.0f + __expf(-x)); }
__device__ inline float ftanh(float x){ float e = __expf(2.0f*x); return 1.0f - 2.0f/(e + 1.0f); }

// 2 batch rows per block, grid (256, n) - max block count (latency-bound, TLP wins)
__global__ __launch_bounds__(256) void cell_batched(CArgs a, const float* __restrict__ wd)
{
  const CellDesc e = a.e[blockIdx.y];
  const int tid = threadIdx.x;
  const int r0 = blockIdx.x * 2;
  __shared__ float dn[2][64];

  if (tid < 128) {
    int r = tid >> 6, k = tid & 63;
    long row = r0 + r;
    float gv = e.gr[row*64 + k];
    if (e.u0) gv += (1.0f/3.0f)*e.u0[row*64 + k];
    if (e.u1) gv += (1.0f/3.0f)*e.u1[row*64 + k];
    float rr = sigm(gv);
    float dv = rr * e.d[row*64 + k];
    e.d[row*64 + k] = dv;
    dn[r][k] = dv;
  }
  __syncthreads();

  float accv[2][2] = {};
#pragma unroll 4
  for (int k = 0; k < 64; ++k) {
    float w0 = wd[k*512 + tid];
    float w1 = wd[k*512 + tid + 256];
#pragma unroll
    for (int r = 0; r < 2; ++r) {
      float dv = dn[r][k];
      accv[0][r] += dv * w0;
      accv[1][r] += dv * w1;
    }
  }

#pragma unroll
  for (int half = 0; half < 2; ++half) {
    int n = tid + half*256;
#pragma unroll
    for (int r = 0; r < 2; ++r) {
      long row = r0 + r;
      const float* gg = e.gate + row*2048;
      float fv = sigm(gg[n]);
      float iv = sigm(gg[512+n]);
      float ov = sigm(gg[1024+n]);
      float cb = ftanh(gg[1536+n]);
      float cv = fv * e.c[row*512 + n] + iv * cb + ftanh(accv[half][r]);
      e.c[row*512 + n] = cv;
      e.hout[row*LDH + n] = __float2bfloat16(ov * ftanh(cv));
    }
  }
}

// ---------------- setup kernels
__global__ void k_tpose2(const float* __restrict__ src, long srow,
                         bf16* __restrict__ dst, long drow, int kcnt, long koff,
                         long total)
{
  long idx = (long)blockIdx.x * 256 + threadIdx.x;
  if (idx >= total) return;
  long n = idx / kcnt;
  long k = idx - n * kcnt;
  dst[n*drow + koff + k] = __float2bfloat16(src[k * srow + n]);
}

__global__ void k_xconv(const float* __restrict__ x, bf16* __restrict__ xb)
{
  long i = (long)blockIdx.x * 256 + threadIdx.x;
  if (i >= (long)TT*BB*512) return;
  int cc = (int)(i & 511);
  long r = i >> 9;
  int t = (int)(r / BB), b = (int)(r - (long)t*BB);
  xb[i] = __float2bfloat16(x[((long)b*TT + t)*512 + cc]);
}

__global__ void k_bias(const float* b0,const float* b1,const float* b2,
                       const float* b3,const float* b4,const float* b5,
                       float* out)
{
  int i = blockIdx.x*256 + threadIdx.x;
  if (i < 2048)      out[i] = b0[i] + b1[i];
  else if (i < 4096) out[i] = b2[i-2048] + b3[i-2048];
  else if (i < 6144) out[i] = b4[i-4096] + b5[i-4096];
}

__global__ void k_dinit(const float* __restrict__ keys, float* __restrict__ d)
{
  int i = blockIdx.x*256 + threadIdx.x;
  if (i < 3*BB*KK) d[i] = keys[i % (BB*KK)];
}

// ---------------- host
extern "C" void kernel_launch(void* const* d_in, const int* in_sizes, int n_in,
                              void* d_out, int out_size, void* d_ws, size_t ws_size,
                              hipStream_t stream)
{
  const float* inputs    = (const float*)d_in[0];
  const float* init_keys = (const float*)d_in[1];
  const float* wx_w[3] = {(const float*)d_in[2],  (const float*)d_in[8],  (const float*)d_in[14]};
  const float* wx_b[3] = {(const float*)d_in[3],  (const float*)d_in[9],  (const float*)d_in[15]};
  const float* wh_w[3] = {(const float*)d_in[4],  (const float*)d_in[10], (const float*)d_in[16]};
  const float* wh_b[3] = {(const float*)d_in[5],  (const float*)d_in[11], (const float*)d_in[17]};
  const float* wr_w[3] = {(const float*)d_in[6],  (const float*)d_in[12], (const float*)d_in[18]};
  const float* wl_w[3] = {(const float*)d_in[7],  (const float*)d_in[13], (const float*)d_in[19]};
  const float* wd_w   = (const float*)d_in[20];
  const float* proj_w = (const float*)d_in[21];
  const float* proj_b = (const float*)d_in[22];
  float* out = (float*)d_out;

  char* wsp = (char*)d_ws;
  size_t used = 0;
  auto alloc = [&](size_t bytes) {
    char* p = wsp + used;
    used += (bytes + 255) & ~(size_t)255;
    return p;
  };
  bf16* xb    = (bf16*)alloc((size_t)TT*BB*512*2);       // [t][b][c]
  bf16* WL0T  = (bf16*)alloc((size_t)2176*1024*2);       // [gate0|gr0|u0] x [x;h0]
  bf16* WL1T  = (bf16*)alloc((size_t)2176*1536*2);       // [gate1|gr1|u1] x [x;h0;h1]
  bf16* WL2T  = (bf16*)alloc((size_t)2176*2048*2);       // [gate2|gr2|pad] x [x;h0;h1;h2]
  bf16* projT = (bf16*)alloc((size_t)512*1536*2);
  bf16* Hall  = (bf16*)alloc((size_t)BB*TT*1536*2);      // FULL h history [b][t][3*512] (86.5 MB)
  bf16* hz    = (bf16*)alloc((size_t)BB*512*2);          // zero h (t=-1 operands)
  float* accg = (float*)alloc((size_t)4*3*BB*2048*4);    // gate rings [slot][l][b][2048]
  float* accr = (float*)alloc((size_t)4*3*BB*64*4);      // gr rings
  float* ubuf = (float*)alloc((size_t)4*2*BB*64*4);      // u rings [slot][j][b][64]
  float* cbuf = (float*)alloc((size_t)3*BB*DD*4);
  float* dbuf = (float*)alloc((size_t)3*BB*KK*4);
  float* biasg= (float*)alloc((size_t)3*2048*4);
  float* dump = (float*)alloc((size_t)BB*64*4);          // pad-column sink
  if (used > ws_size) return;

  const long SZG = (long)BB*2048;
  const long SZR = (long)BB*64;

  auto slotg = [&](int s, int l){ return accg + (long)((s&3)*3+l)*SZG; };
  auto slotr = [&](int s, int l){ return accr + (long)((s&3)*3+l)*SZR; };
  auto slotu = [&](int s, int j){ return ubuf + (long)((s&3)*2+j)*SZR; };
  auto hb    = [&](int s){ return Hall + (long)s*1536; };

  // ---- setup
  {
    long tot = (long)TT*BB*512;
    k_xconv<<<dim3((tot + 255)/256), 256, 0, stream>>>(inputs, xb);
  }
  hipMemsetAsync(WL0T, 0, (size_t)2176*1024*2, stream);
  hipMemsetAsync(WL1T, 0, (size_t)2176*1536*2, stream);
  hipMemsetAsync(WL2T, 0, (size_t)2176*2048*2, stream);
  hipMemsetAsync(hz,   0, (size_t)BB*512*2, stream);
  hipMemsetAsync(cbuf, 0, (size_t)3*BB*DD*4, stream);

  auto tp2 = [&](const float* src, long kOffSrc, long srow,
                 bf16* dst, long colbase, long drow, long koff, int N){
    long total = (long)N*512;
    k_tpose2<<<dim3((total + 255)/256), 256, 0, stream>>>(
        src + kOffSrc*srow, srow, dst + colbase*drow, drow, 512, koff, total);
  };
  // WL0T (drow=1024, K=[x(512);h0(512)]): cols [gate0 2048 | gr0 64 | u0 64]
  tp2(wx_w[0],0,2048, WL0T,0,1024,0,2048);
  tp2(wh_w[0],0,2048, WL0T,0,1024,512,2048);
  tp2(wr_w[0],0,64,   WL0T,2048,1024,0,64);
  tp2(wl_w[0],0,64,   WL0T,2112,1024,512,64);
  // WL1T (drow=1536, K=[x;h0;h1]): cols [gate1 2048 | gr1 64 | u1 64]
  tp2(wx_w[1],0,2048,   WL1T,0,1536,0,2048);
  tp2(wx_w[1],512,2048, WL1T,0,1536,512,2048);
  tp2(wh_w[1],0,2048,   WL1T,0,1536,1024,2048);
  tp2(wr_w[1],0,64,     WL1T,2048,1536,0,64);
  tp2(wr_w[1],512,64,   WL1T,2048,1536,512,64);
  tp2(wl_w[1],0,64,     WL1T,2112,1536,1024,64);
  // WL2T (drow=2048, K=[x;h0;h1;h2]): cols [gate2 2048 | gr2 64 | pad 64]
  tp2(wx_w[2],0,2048,    WL2T,0,2048,0,2048);
  tp2(wx_w[2],512,2048,  WL2T,0,2048,512,2048);
  tp2(wx_w[2],1024,2048, WL2T,0,2048,1024,2048);
  tp2(wh_w[2],0,2048,    WL2T,0,2048,1536,2048);
  tp2(wr_w[2],0,64,      WL2T,2048,2048,0,64);
  tp2(wr_w[2],512,64,    WL2T,2048,2048,512,64);
  tp2(wr_w[2],1024,64,   WL2T,2048,2048,1024,64);
  // projT (drow=1536, K=[h0;h1;h2])
  {
    long total = (long)512*1536;
    k_tpose2<<<dim3((total + 255)/256), 256, 0, stream>>>(
        proj_w, 512, projT, 1536, 1536, 0, total);
  }

  k_bias<<<dim3(24),256,0,stream>>>(wx_b[0],wh_b[0],wx_b[1],wh_b[1],wx_b[2],wh_b[2], biasg);
  k_dinit<<<dim3((3*BB*KK + 255)/256),256,0,stream>>>(init_keys, dbuf);

  // ---- pipelined recurrence. Phase t:
  //   A(t): cells {E0(t), E1(t-1), E2(t-2)}
  //   B(t): L0 -> gate0/gr0(t+1), u0(t)   A=[x(t+1); h0(t)]        K=1024
  //         L1 -> gate1/gr1(t),   u1(t-1) A=[x(t); h0(t); h1(t-1)] K=1536
  //         L2 -> gate2/gr2(t-1)          A=[x(t-1); h0..h1(t-1); h2(t-2)] K=2048
  // Projection is OUT of the loop (full h history kept): one saturated GEMM at
  // the end instead of 57 small under-occupied groups on the critical cadence.
  // h(-1)=hz (zeros); L0(-1)/L1(0) write the zero u0(-1)/u1(-1) slots.
  for (int t = -1; t <= TT + 1; ++t) {
    // ----- A phase
    CArgs ca{}; ca.n = 0;
    auto addE = [&](int s, int l){
      CellDesc& e = ca.e[ca.n++];
      e.gate = slotg(s,l);
      e.gr   = slotr(s,l);
      e.u0 = (l>=1) ? slotu(s-1,0) : nullptr;
      e.u1 = (l>=2) ? slotu(s-1,1) : nullptr;
      e.c = cbuf + (long)l*BB*DD; e.d = dbuf + (long)l*BB*KK;
      e.hout = hb(s) + (long)l*512;
    };
    if (t   >= 0 && t   < TT) addE(t,   0);
    if (t-1 >= 0 && t-1 < TT) addE(t-1, 1);
    if (t-2 >= 0 && t-2 < TT) addE(t-2, 2);
    if (ca.n)
      cell_batched<<<dim3(256, ca.n), 256, 0, stream>>>(ca, wd_w);

    // ----- B phase
    GArgs ga{}; ga.ng = 0;
    int cursor = 0;
    auto addG = [&](const bf16* B, long ldb, int mtiles, int ntiles, int Kd, SegList sl,
                    const bf16* a0, long l0, const bf16* a1, long l1,
                    const bf16* a2, long l2, const bf16* a3, long l3){
      GDesc& g = ga.g[ga.ng++];
      g.Ap[0]=a0; g.Ap[1]=a1; g.Ap[2]=a2; g.Ap[3]=a3;
      g.ldap[0]=l0; g.ldap[1]=l1; g.ldap[2]=l2; g.ldap[3]=l3;
      g.B = B; g.ldb = ldb;
      g.mtiles = mtiles; g.ntiles = ntiles; g.tile_beg = cursor; g.K = Kd;
      cursor += mtiles * ntiles;
      g.segs = sl;
    };
    if (t >= -1 && t <= TT-2) {        // L0 -> step t+1
      SegList sl{}; sl.n = 3;
      sl.s[0] = { slotg(t+1,0), 2048,    0, 0, biasg + 0 };
      sl.s[1] = { slotr(t+1,0),   64, 2048, 0, nullptr   };
      sl.s[2] = { slotu(t,0),     64, 2112, 0, nullptr   };
      addG(WL0T, 1024, 8, 34, 1024, sl,
           xb + (long)(t+1)*BB*512, 512,
           (t>=0)? hb(t) : hz, (t>=0)? LDH : 512,
           nullptr,0, nullptr,0);
    }
    if (t >= 0 && t <= TT-1) {         // L1 -> step t
      SegList sl{}; sl.n = 3;
      sl.s[0] = { slotg(t,1),   2048,    0, 0, biasg + 2048 };
      sl.s[1] = { slotr(t,1),     64, 2048, 0, nullptr      };
      sl.s[2] = { slotu(t-1,1),   64, 2112, 0, nullptr      };
      addG(WL1T, 1536, 8, 34, 1536, sl,
           xb + (long)t*BB*512, 512,
           hb(t), LDH,
           (t>=1)? hb(t-1)+512 : hz, (t>=1)? LDH : 512,
           nullptr,0);
    }
    if (t >= 1 && t <= TT) {           // L2 -> step s=t-1
      int s = t-1;
      SegList sl{}; sl.n = 3;
      sl.s[0] = { slotg(s,2), 2048,    0, 0, biasg + 4096 };
      sl.s[1] = { slotr(s,2),   64, 2048, 0, nullptr      };
      sl.s[2] = { dump,         64, 2112, 0, nullptr      };
      addG(WL2T, 2048, 8, 34, 2048, sl,
           xb + (long)s*BB*512, 512,
           hb(s), LDH,
           hb(s)+512, LDH,
           (s>=1)? hb(s-1)+1024 : hz, (s>=1)? LDH : 512);
    }
    if (cursor) {
      ga.total = cursor; ga.chunk = (cursor + 7) / 8;
      gemm_batched<<<dim3(ga.chunk * 8), 256, 0, stream>>>(ga);
    }
  }

  // ---- projection, one saturated dispatch: out[(b,t)][n] = h[(b,t)] @ proj + b
  // Hall is [b][t][1536] so GEMM row m = b*TT+t is at Hall + m*1536 (lda=1536),
  // matching out rows at out + m*512 (ldd=512). M=28160, N=512, K=1536.
  {
    GArgs ga{}; ga.ng = 1;
    GDesc& g = ga.g[0];
    g.Ap[0] = Hall;        g.ldap[0] = 1536;
    g.Ap[1] = Hall + 512;  g.ldap[1] = 1536;
    g.Ap[2] = Hall + 1024; g.ldap[2] = 1536;
    g.Ap[3] = nullptr;     g.ldap[3] = 0;
    g.B = projT; g.ldb = 1536;
    g.mtiles = (BB*TT)/64; g.ntiles = 8; g.tile_beg = 0; g.K = 1536;
    g.segs.n = 1;
    g.segs.s[0] = { out, 512, 0, 0, proj_b };
    ga.total = g.mtiles * g.ntiles; ga.chunk = (ga.total + 7) / 8;
    gemm_batched<<<dim3(ga.chunk * 8), 256, 0, stream>>>(ga);
  }
}

// Round 13
// 2498.394 us; speedup vs baseline: 11.4972x; 1.0203x over previous
//
#include <hip/hip_runtime.h>
#include <hip/hip_bf16.h>

typedef __hip_bfloat16 bf16;
typedef __attribute__((ext_vector_type(8))) short s16x8;
typedef __attribute__((ext_vector_type(4))) float f32x4;

// Problem constants
#define TT 55
#define BB 512
#define DD 512
#define KK 64
#define LDH ((long)TT*1536)      // h buffer row stride (all 55 steps kept)

typedef const __attribute__((address_space(1))) unsigned int gu32;
typedef __attribute__((address_space(3))) unsigned int lu32;
__device__ __forceinline__ void gload16(const void* g, void* l) {
  __builtin_amdgcn_global_load_lds((gu32*)g, (lu32*)l, 16, 0, 0);
}

struct Seg {
  void*  dst;          // destination base
  long   ldd;          // row stride (elements)
  int    col_begin;    // inclusive (GEMM N space), 64-aligned, sorted asc
  int    mode;         // 0 = f32 store (+bias)
  const float* bias;   // indexed by (col - col_begin), may be null
};
struct SegList { Seg s[4]; int n; };

// A operand is split into up to 4 K-parts of exactly 512 columns each
// (x slice / h slices / zero buffer). B is one stacked-transposed buffer.
struct GDesc {
  const bf16* Ap[4]; const bf16* B;
  long ldap[4], ldb;
  int mtiles, ntiles, tile_beg, K, order;  // order 0: mt-fast (B-panel reuse)
                                           // order 1: nt-fast (A-panel reuse; proj)
  SegList segs;
};
struct GArgs { GDesc g[4]; int ng; int total; int chunk; };

// ---------------- batched GEMM: C[seg] = sum_p Ap[MxK_p] * B^T[NxK], bf16, fp32 acc
// 64x64 tile (r7 session optimum), BK=64, 4 waves (2x2 of 32x32), 32 KB LDS,
// depth-1 double buffer with counted vmcnt(4). Equal-block-count XCD chunks.
// LDS XOR-swizzled (block p of row r holds global block p^(r&7)).
__global__ __launch_bounds__(256) void gemm_batched(GArgs args)
{
  __shared__ __align__(16) bf16 As[2][64][64];    // 2 x 8 KB
  __shared__ __align__(16) bf16 Bs[2][64][64];    // 2 x 8 KB

  int tile = (int)(blockIdx.x & 7) * args.chunk + (int)(blockIdx.x >> 3);
  if (tile >= args.total) return;

  int gi = 0;
  for (int i = 1; i < args.ng; ++i) if (tile >= args.g[i].tile_beg) gi = i;
  const GDesc& g = args.g[gi];
  const int local = tile - g.tile_beg;
  int mt, nt;
  if (g.order) { nt = local % g.ntiles; mt = local / g.ntiles; }  // A-panel reuse
  else         { mt = local % g.mtiles; nt = local / g.mtiles; }  // B-panel reuse

  const int tid  = threadIdx.x;
  const int wave = tid >> 6, lane = tid & 63;
  const int q = lane >> 4, mm = lane & 15;
  const int s7 = mm & 7;
  const int wm = wave >> 1, wn = wave & 1;
  const long m0 = (long)mt * 64;
  const long n0 = (long)nt * 64;

  const bf16* Bb = g.B + n0 * g.ldb;
  const long ldb = g.ldb;
  const int l8 = lane >> 3;                 // row within 8-row staging group
  const int gc = ((lane & 7) ^ l8) << 3;    // swizzled global col (elements)

  const int nk = g.K >> 6;                  // K-steps

  auto stage = [&](int b, int k0) {
    const int p = k0 >> 9;                  // 512-wide K-parts; 64-steps never cross
    const long ldap = g.ldap[p];
    const bf16* Abp = g.Ap[p] + m0 * ldap;
    const int ko = k0 & 511;
#pragma unroll
    for (int pp = 0; pp < 2; ++pp) {
      int r = pp*32 + wave*8;
      gload16(Abp + (long)(r + l8)*ldap + ko + gc, &As[b][r][0]);
    }
#pragma unroll
    for (int pp = 0; pp < 2; ++pp) {
      int r = pp*32 + wave*8;
      gload16(Bb + (long)(r + l8)*ldb + k0 + gc, &Bs[b][r][0]);
    }
  };

  f32x4 acc[2][2] = {};

  stage(0, 0);                              // 4 loads in flight
  for (int k = 0; k < nk; ++k) {
    const int cur = k & 1;
    if (k + 1 < nk) {
      stage(cur ^ 1, (k + 1) << 6);         // 8 in flight
      asm volatile("s_waitcnt vmcnt(4)" ::: "memory");   // k's 4 landed
    } else {
      asm volatile("s_waitcnt vmcnt(0)" ::: "memory");
    }
    __builtin_amdgcn_s_barrier();           // all waves' k-data in LDS
#pragma unroll
    for (int kk = 0; kk < 64; kk += 32) {
      const int pc = ((((kk >> 3) + q) ^ s7) << 3);  // physical col of logical kk+q*8
      s16x8 av[2], bv[2];
#pragma unroll
      for (int i = 0; i < 2; ++i) av[i] = *(const s16x8*)&As[cur][wm*32 + i*16 + mm][pc];
#pragma unroll
      for (int j = 0; j < 2; ++j) bv[j] = *(const s16x8*)&Bs[cur][wn*32 + j*16 + mm][pc];
#pragma unroll
      for (int i = 0; i < 2; ++i)
#pragma unroll
        for (int j = 0; j < 2; ++j)
          acc[i][j] = __builtin_amdgcn_mfma_f32_16x16x32_bf16(av[i], bv[j], acc[i][j], 0,0,0);
    }
    __builtin_amdgcn_s_barrier();           // buf cur free for restage at k+2
  }

  // epilogue: 64-wide tile lies in ONE segment (boundaries 64-aligned)
  Seg sg = g.segs.s[0];
  for (int i = 1; i < g.segs.n; ++i)
    if ((int)n0 >= g.segs.s[i].col_begin) sg = g.segs.s[i];
#pragma unroll
  for (int j = 0; j < 2; ++j) {
    int dcol = (int)n0 + wn*32 + j*16 + mm - sg.col_begin;
    float bv = sg.bias ? sg.bias[dcol] : 0.0f;
#pragma unroll
    for (int i = 0; i < 2; ++i) {
      f32x4 a = acc[i][j];
#pragma unroll
      for (int r = 0; r < 4; ++r) {
        long row = m0 + wm*32 + i*16 + q*4 + r;  // C/D: col=lane&15, row=q*4+reg
        ((float*)sg.dst)[row * sg.ldd + dcol] = a[r] + bv;
      }
    }
  }
}

// ---------------- batched cell update: up to 3 independent (step,layer) cells
struct CellDesc {
  const float* gate;   // fp32 ring [512][2048] - complete (bias + all parts)
  const float* gr;     // fp32 [512][64] - complete x+h parts
  const float* u0;     // may be null (ALPHA-scaled in cell)
  const float* u1;     // may be null
  float* c;            // [512][512]
  float* d;            // [512][64]
  bf16*  hout;         // row stride LDH
};
struct CArgs { CellDesc e[3]; int n; };

__device__ inline float sigm(float x){ return 1.0f/(1.0f + __expf(-x)); }
__device__ inline float ftanh(float x){ float e = __expf(2.0f*x); return 1.0f - 2.0f/(e + 1.0f); }

// 2 batch rows per block, grid (256, n) - max block count (latency-bound, TLP wins)
__global__ __launch_bounds__(256) void cell_batched(CArgs a, const float* __restrict__ wd)
{
  const CellDesc e = a.e[blockIdx.y];
  const int tid = threadIdx.x;
  const int r0 = blockIdx.x * 2;
  __shared__ float dn[2][64];

  if (tid < 128) {
    int r = tid >> 6, k = tid & 63;
    long row = r0 + r;
    float gv = e.gr[row*64 + k];
    if (e.u0) gv += (1.0f/3.0f)*e.u0[row*64 + k];
    if (e.u1) gv += (1.0f/3.0f)*e.u1[row*64 + k];
    float rr = sigm(gv);
    float dv = rr * e.d[row*64 + k];
    e.d[row*64 + k] = dv;
    dn[r][k] = dv;
  }
  __syncthreads();

  float accv[2][2] = {};
#pragma unroll 4
  for (int k = 0; k < 64; ++k) {
    float w0 = wd[k*512 + tid];
    float w1 = wd[k*512 + tid + 256];
#pragma unroll
    for (int r = 0; r < 2; ++r) {
      float dv = dn[r][k];
      accv[0][r] += dv * w0;
      accv[1][r] += dv * w1;
    }
  }

#pragma unroll
  for (int half = 0; half < 2; ++half) {
    int n = tid + half*256;
#pragma unroll
    for (int r = 0; r < 2; ++r) {
      long row = r0 + r;
      const float* gg = e.gate + row*2048;
      float fv = sigm(gg[n]);
      float iv = sigm(gg[512+n]);
      float ov = sigm(gg[1024+n]);
      float cb = ftanh(gg[1536+n]);
      float cv = fv * e.c[row*512 + n] + iv * cb + ftanh(accv[half][r]);
      e.c[row*512 + n] = cv;
      e.hout[row*LDH + n] = __float2bfloat16(ov * ftanh(cv));
    }
  }
}

// ---------------- setup kernels
// single merged transpose kernel: 18 jobs, each dst[n*drow+koff+k] = src[k*srow+n]
struct TpJob { const float* src; bf16* dst; long srow, drow, koff, kcnt, blk_beg; };
struct TpArgs { TpJob j[18]; int nj; };

__global__ void k_tposeAll(TpArgs a)
{
  long blk = blockIdx.x;
  int ji = 0;
  for (int i = 1; i < a.nj; ++i) if (blk >= a.j[i].blk_beg) ji = i;
  const TpJob& J = a.j[ji];
  long e = (blk - J.blk_beg)*256 + threadIdx.x;
  long n = e / J.kcnt;
  long k = e - n * J.kcnt;
  // jobs are launched with exact block counts per job; guard the tail block
  long nmax = (ji + 1 < a.nj) ? 0 : 0;  // bound enforced via total elems below
  (void)nmax;
  long total = (((ji + 1 < a.nj) ? a.j[ji+1].blk_beg : (long)gridDim.x) - J.blk_beg)*256;
  // total >= elems; guard by computed n bound:
  if (e >= ((total)) ) return;
  // exact element bound: n must be < (elems/kcnt); elems = rounded up, so check:
  if (n * J.kcnt + k >= ((total/256)*256)) {}  // no-op; real guard below
  if (e >= (long)(( ( ( (total) ) ) ))) return;
  // safe guard: only write if within the job's logical element count
  // (stored implicitly: the next job's blk_beg is ceil(elems/256), so the last
  //  block may overrun; cap via kcnt-aligned n limit passed through koff? )
  // -> explicit elems field avoided by storing it in srow sign? Keep it simple:
  //    jobs always have elems % 256 handled by the n-range check:
  if (n >= (total + J.kcnt - 1) / J.kcnt) return;   // conservative row cap
  // final exact guard: recompute with true elems = (exact) stored in blk pad
  J.dst[n*J.drow + J.koff + k] = __float2bfloat16(J.src[k*J.srow + n]);
}

__global__ void k_xconv(const float* __restrict__ x, bf16* __restrict__ xb)
{
  long i = (long)blockIdx.x * 256 + threadIdx.x;
  if (i >= (long)TT*BB*512) return;
  int cc = (int)(i & 511);
  long r = i >> 9;
  int t = (int)(r / BB), b = (int)(r - (long)t*BB);
  xb[i] = __float2bfloat16(x[((long)b*TT + t)*512 + cc]);
}

__global__ void k_bias(const float* b0,const float* b1,const float* b2,
                       const float* b3,const float* b4,const float* b5,
                       float* out)
{
  int i = blockIdx.x*256 + threadIdx.x;
  if (i < 2048)      out[i] = b0[i] + b1[i];
  else if (i < 4096) out[i] = b2[i-2048] + b3[i-2048];
  else if (i < 6144) out[i] = b4[i-4096] + b5[i-4096];
}

__global__ void k_dinit(const float* __restrict__ keys, float* __restrict__ d)
{
  int i = blockIdx.x*256 + threadIdx.x;
  if (i < 3*BB*KK) d[i] = keys[i % (BB*KK)];
}

// ---------------- host
extern "C" void kernel_launch(void* const* d_in, const int* in_sizes, int n_in,
                              void* d_out, int out_size, void* d_ws, size_t ws_size,
                              hipStream_t stream)
{
  const float* inputs    = (const float*)d_in[0];
  const float* init_keys = (const float*)d_in[1];
  const float* wx_w[3] = {(const float*)d_in[2],  (const float*)d_in[8],  (const float*)d_in[14]};
  const float* wx_b[3] = {(const float*)d_in[3],  (const float*)d_in[9],  (const float*)d_in[15]};
  const float* wh_w[3] = {(const float*)d_in[4],  (const float*)d_in[10], (const float*)d_in[16]};
  const float* wh_b[3] = {(const float*)d_in[5],  (const float*)d_in[11], (const float*)d_in[17]};
  const float* wr_w[3] = {(const float*)d_in[6],  (const float*)d_in[12], (const float*)d_in[18]};
  const float* wl_w[3] = {(const float*)d_in[7],  (const float*)d_in[13], (const float*)d_in[19]};
  const float* wd_w   = (const float*)d_in[20];
  const float* proj_w = (const float*)d_in[21];
  const float* proj_b = (const float*)d_in[22];
  float* out = (float*)d_out;

  char* wsp = (char*)d_ws;
  size_t used = 0;
  auto alloc = [&](size_t bytes) {
    char* p = wsp + used;
    used += (bytes + 255) & ~(size_t)255;
    return p;
  };
  bf16* xb    = (bf16*)alloc((size_t)TT*BB*512*2);       // [t][b][c]
  bf16* WL0T  = (bf16*)alloc((size_t)2176*1024*2);       // [gate0|gr0|u0] x [x;h0]
  bf16* WL1T  = (bf16*)alloc((size_t)2176*1536*2);       // [gate1|gr1|u1] x [x;h0;h1]
  bf16* WL2T  = (bf16*)alloc((size_t)2176*2048*2);       // [gate2|gr2|pad] x [x;h0;h1;h2]
  bf16* projT = (bf16*)alloc((size_t)512*1536*2);
  bf16* Hall  = (bf16*)alloc((size_t)BB*TT*1536*2);      // FULL h history [b][t][3*512]
  bf16* hz    = (bf16*)alloc((size_t)BB*512*2);          // zero h (t=-1 operands)
  float* accg = (float*)alloc((size_t)4*3*BB*2048*4);    // gate rings [slot][l][b][2048]
  float* accr = (float*)alloc((size_t)4*3*BB*64*4);      // gr rings
  float* ubuf = (float*)alloc((size_t)4*2*BB*64*4);      // u rings [slot][j][b][64]
  float* cbuf = (float*)alloc((size_t)3*BB*DD*4);
  float* dbuf = (float*)alloc((size_t)3*BB*KK*4);
  float* biasg= (float*)alloc((size_t)3*2048*4);
  float* dump = (float*)alloc((size_t)BB*64*4);          // pad-column sink
  if (used > ws_size) return;

  const long SZG = (long)BB*2048;
  const long SZR = (long)BB*64;

  auto slotg = [&](int s, int l){ return accg + (long)((s&3)*3+l)*SZG; };
  auto slotr = [&](int s, int l){ return accr + (long)((s&3)*3+l)*SZR; };
  auto slotu = [&](int s, int j){ return ubuf + (long)((s&3)*2+j)*SZR; };
  auto hb    = [&](int s){ return Hall + (long)s*1536; };

  // ---- setup
  {
    long tot = (long)TT*BB*512;
    k_xconv<<<dim3((tot + 255)/256), 256, 0, stream>>>(inputs, xb);
  }
  hipMemsetAsync(WL0T, 0, (size_t)2176*1024*2, stream);
  hipMemsetAsync(WL1T, 0, (size_t)2176*1536*2, stream);
  hipMemsetAsync(WL2T, 0, (size_t)2176*2048*2, stream);
  hipMemsetAsync(hz,   0, (size_t)BB*512*2, stream);
  hipMemsetAsync(cbuf, 0, (size_t)3*BB*DD*4, stream);

  // merged transpose: 18 jobs in one launch
  {
    TpArgs ta{}; long blk = 0; int nj = 0;
    auto addJ = [&](const float* src, long kOffSrc, long srow,
                    bf16* dst, long colbase, long drow, long koff, long N, long kcnt){
      TpJob& J = ta.j[nj++];
      J.src = src + kOffSrc*srow; J.srow = srow;
      J.dst = dst + colbase*drow; J.drow = drow; J.koff = koff; J.kcnt = kcnt;
      J.blk_beg = blk;
      blk += (N*kcnt + 255) / 256;           // N*kcnt always %256==0 here
    };
    // WL0T (drow=1024, K=[x;h0]): cols [gate0 2048 | gr0 64 | u0 64]
    addJ(wx_w[0],0,2048, WL0T,0,1024,0,2048,512);
    addJ(wh_w[0],0,2048, WL0T,0,1024,512,2048,512);
    addJ(wr_w[0],0,64,   WL0T,2048,1024,0,64,512);
    addJ(wl_w[0],0,64,   WL0T,2112,1024,512,64,512);
    // WL1T (drow=1536, K=[x;h0;h1])
    addJ(wx_w[1],0,2048,   WL1T,0,1536,0,2048,512);
    addJ(wx_w[1],512,2048, WL1T,0,1536,512,2048,512);
    addJ(wh_w[1],0,2048,   WL1T,0,1536,1024,2048,512);
    addJ(wr_w[1],0,64,     WL1T,2048,1536,0,64,512);
    addJ(wr_w[1],512,64,   WL1T,2048,1536,512,64,512);
    addJ(wl_w[1],0,64,     WL1T,2112,1536,1024,64,512);
    // WL2T (drow=2048, K=[x;h0;h1;h2])
    addJ(wx_w[2],0,2048,    WL2T,0,2048,0,2048,512);
    addJ(wx_w[2],512,2048,  WL2T,0,2048,512,2048,512);
    addJ(wx_w[2],1024,2048, WL2T,0,2048,1024,2048,512);
    addJ(wh_w[2],0,2048,    WL2T,0,2048,1536,2048,512);
    addJ(wr_w[2],0,64,      WL2T,2048,2048,0,64,512);
    addJ(wr_w[2],512,64,    WL2T,2048,2048,512,64,512);
    addJ(wr_w[2],1024,64,   WL2T,2048,2048,1024,64,512);
    // projT (drow=1536, K=[h0;h1;h2]): N=512, kcnt=1536
    addJ(proj_w,0,512, projT,0,1536,0,512,1536);
    ta.nj = nj;
    k_tposeAll<<<dim3((unsigned)blk), 256, 0, stream>>>(ta);
  }

  k_bias<<<dim3(24),256,0,stream>>>(wx_b[0],wh_b[0],wx_b[1],wh_b[1],wx_b[2],wh_b[2], biasg);
  k_dinit<<<dim3((3*BB*KK + 255)/256),256,0,stream>>>(init_keys, dbuf);

  // ---- pipelined recurrence. Phase t:
  //   A(t): cells {E0(t), E1(t-1), E2(t-2)}
  //   B(t): L0 -> gate0/gr0(t+1), u0(t)   A=[x(t+1); h0(t)]        K=1024
  //         L1 -> gate1/gr1(t),   u1(t-1) A=[x(t); h0(t); h1(t-1)] K=1536
  //         L2 -> gate2/gr2(t-1)          A=[x(t-1); h0..h1(t-1); h2(t-2)] K=2048
  // Projection is OUT of the loop (full h history kept).
  // h(-1)=hz (zeros); L0(-1)/L1(0) write the zero u0(-1)/u1(-1) slots.
  for (int t = -1; t <= TT + 1; ++t) {
    // ----- A phase
    CArgs ca{}; ca.n = 0;
    auto addE = [&](int s, int l){
      CellDesc& e = ca.e[ca.n++];
      e.gate = slotg(s,l);
      e.gr   = slotr(s,l);
      e.u0 = (l>=1) ? slotu(s-1,0) : nullptr;
      e.u1 = (l>=2) ? slotu(s-1,1) : nullptr;
      e.c = cbuf + (long)l*BB*DD; e.d = dbuf + (long)l*BB*KK;
      e.hout = hb(s) + (long)l*512;
    };
    if (t   >= 0 && t   < TT) addE(t,   0);
    if (t-1 >= 0 && t-1 < TT) addE(t-1, 1);
    if (t-2 >= 0 && t-2 < TT) addE(t-2, 2);
    if (ca.n)
      cell_batched<<<dim3(256, ca.n), 256, 0, stream>>>(ca, wd_w);

    // ----- B phase
    GArgs ga{}; ga.ng = 0;
    int cursor = 0;
    auto addG = [&](const bf16* B, long ldb, int mtiles, int ntiles, int Kd, SegList sl,
                    const bf16* a0, long l0, const bf16* a1, long l1,
                    const bf16* a2, long l2, const bf16* a3, long l3){
      GDesc& g = ga.g[ga.ng++];
      g.Ap[0]=a0; g.Ap[1]=a1; g.Ap[2]=a2; g.Ap[3]=a3;
      g.ldap[0]=l0; g.ldap[1]=l1; g.ldap[2]=l2; g.ldap[3]=l3;
      g.B = B; g.ldb = ldb;
      g.mtiles = mtiles; g.ntiles = ntiles; g.tile_beg = cursor; g.K = Kd; g.order = 0;
      cursor += mtiles * ntiles;
      g.segs = sl;
    };
    if (t >= -1 && t <= TT-2) {        // L0 -> step t+1
      SegList sl{}; sl.n = 3;
      sl.s[0] = { slotg(t+1,0), 2048,    0, 0, biasg + 0 };
      sl.s[1] = { slotr(t+1,0),   64, 2048, 0, nullptr   };
      sl.s[2] = { slotu(t,0),     64, 2112, 0, nullptr   };
      addG(WL0T, 1024, 8, 34, 1024, sl,
           xb + (long)(t+1)*BB*512, 512,
           (t>=0)? hb(t) : hz, (t>=0)? LDH : 512,
           nullptr,0, nullptr,0);
    }
    if (t >= 0 && t <= TT-1) {         // L1 -> step t
      SegList sl{}; sl.n = 3;
      sl.s[0] = { slotg(t,1),   2048,    0, 0, biasg + 2048 };
      sl.s[1] = { slotr(t,1),     64, 2048, 0, nullptr      };
      sl.s[2] = { slotu(t-1,1),   64, 2112, 0, nullptr      };
      addG(WL1T, 1536, 8, 34, 1536, sl,
           xb + (long)t*BB*512, 512,
           hb(t), LDH,
           (t>=1)? hb(t-1)+512 : hz, (t>=1)? LDH : 512,
           nullptr,0);
    }
    if (t >= 1 && t <= TT) {           // L2 -> step s=t-1
      int s = t-1;
      SegList sl{}; sl.n = 3;
      sl.s[0] = { slotg(s,2), 2048,    0, 0, biasg + 4096 };
      sl.s[1] = { slotr(s,2),   64, 2048, 0, nullptr      };
      sl.s[2] = { dump,         64, 2112, 0, nullptr      };
      addG(WL2T, 2048, 8, 34, 2048, sl,
           xb + (long)s*BB*512, 512,
           hb(s), LDH,
           hb(s)+512, LDH,
           (s>=1)? hb(s-1)+1024 : hz, (s>=1)? LDH : 512);
    }
    if (cursor) {
      ga.total = cursor; ga.chunk = (cursor + 7) / 8;
      gemm_batched<<<dim3(ga.chunk * 8), 256, 0, stream>>>(ga);
    }
  }

  // ---- projection, one saturated dispatch: out[(b,t)][n] = h[(b,t)] @ proj + b
  // Hall rows m = b*TT+t at Hall + m*1536, out rows at out + m*512.
  // order=1 (nt-fast): consecutive tiles share the 192 KB A panel (L2-resident),
  // so Hall streams ONCE (r12's mt-fast order re-streamed it 8x: FETCH 341 MB).
  {
    GArgs ga{}; ga.ng = 1;
    GDesc& g = ga.g[0];
    g.Ap[0] = Hall;        g.ldap[0] = 1536;
    g.Ap[1] = Hall + 512;  g.ldap[1] = 1536;
    g.Ap[2] = Hall + 1024; g.ldap[2] = 1536;
    g.Ap[3] = nullptr;     g.ldap[3] = 0;
    g.B = projT; g.ldb = 1536;
    g.mtiles = (BB*TT)/64; g.ntiles = 8; g.tile_beg = 0; g.K = 1536; g.order = 1;
    g.segs.n = 1;
    g.segs.s[0] = { out, 512, 0, 0, proj_b };
    ga.total = g.mtiles * g.ntiles; ga.chunk = (ga.total + 7) / 8;
    gemm_batched<<<dim3(ga.chunk * 8), 256, 0, stream>>>(ga);
  }
}